// Round 1
// baseline (2778.437 us; speedup 1.0000x reference)
//
#include <hip/hip_runtime.h>
#include <hip/hip_bf16.h>
#include <stdint.h>

// SNN forward (snntorch Leaky, subtract reset), T=1024 B=128 NIN=256 HID=1024.
// d_out layout: out_spikes [T,B,2] (262144) | hidden_spikes [T,B,HID] (134217728) | mem2_f [B,2] (256)
//
// Pipeline (all on `stream`, no global sync needed):
//   k_transpose: W1 [HID,NIN] -> W1T [NIN,HID]         (ws +0,   1 MB)
//   k_pack:      x [T,B,NIN] f32 0/1 -> u64 bitmasks   (ws +1MB, 4 MB)
//   k_snn:       per-(b, j-chunk) persistent loop over t; sparse gather-sum from
//                LDS-resident W1T chunk; writes hidden spikes + layer-2 partials
//                                                      (part: ws +5MB, 16 MB)
//   k_h2:        reduce 16 j-chunk partials -> h2[t,b,o]  (ws +21MB, 1 MB)
//   k_scan:      mem2 recurrence over t, writes out_spikes + mem2_f

#define TT  1024
#define BB  128
#define NIN 256
#define HID 1024

#define OFF_HID  262144ULL
#define OFF_MEM2 134479872ULL

__global__ __launch_bounds__(256) void k_transpose(const float* __restrict__ W1,
                                                   float* __restrict__ W1T) {
    int idx = blockIdx.x * 256 + threadIdx.x;     // 262144 elements
    int j = idx & (HID - 1);
    int i = idx >> 10;
    W1T[(size_t)i * HID + j] = W1[(size_t)j * NIN + i];
}

__global__ __launch_bounds__(256) void k_pack(const float* __restrict__ x,
                                              unsigned long long* __restrict__ masks) {
    size_t tb = blockIdx.x;                       // T*B blocks
    float v = x[tb * NIN + threadIdx.x];
    unsigned long long m = __ballot(v > 0.5f);
    if ((threadIdx.x & 63) == 0) masks[tb * 4 + (threadIdx.x >> 6)] = m;
}

// One wave = one batch b, 64 lanes = 64 consecutive j. Workgroup = 4 waves (4 b's)
// sharing one 64-wide j-chunk of W1T staged in LDS (64 KB). Grid = 32 bgroups x 16 jchunks.
__global__ __launch_bounds__(256) void k_snn(const float* __restrict__ W1T,
                                             const unsigned long long* __restrict__ masks,
                                             const float* __restrict__ b1,
                                             const float* __restrict__ W2,
                                             float* __restrict__ outHid,
                                             float* __restrict__ part) {
#pragma clang fp contract(off)
    const int jc   = blockIdx.x & 15;
    const int bg   = blockIdx.x >> 4;
    const int lane = threadIdx.x & 63;
    const int wave = threadIdx.x >> 6;
    const int b    = (bg << 2) + wave;
    const int j    = (jc << 6) + lane;

    __shared__ float sW[NIN * 64];                // 64 KB: W1T[:, jc*64 .. +64)
    for (int r = threadIdx.x; r < NIN * 16; r += 256) {
        int i = r >> 4, q = r & 15;
        float4 v = *reinterpret_cast<const float4*>(W1T + (size_t)i * HID + (jc << 6) + (q << 2));
        *reinterpret_cast<float4*>(sW + i * 64 + (q << 2)) = v;
    }
    __syncthreads();

    float mem       = 0.0f;
    const float bias = b1[j];
    const float w20  = W2[j];                     // W2[0][j]
    const float w21  = W2[HID + j];               // W2[1][j]
    const int   ub   = __builtin_amdgcn_readfirstlane(b);

    for (int t = 0; t < TT; ++t) {
        const uint32_t* mp = reinterpret_cast<const uint32_t*>(masks + ((size_t)t * BB + ub) * 4);
        float h = bias;
#pragma unroll
        for (int w = 0; w < 4; ++w) {
            uint32_t lo = __builtin_amdgcn_readfirstlane(mp[2 * w]);
            uint32_t hi = __builtin_amdgcn_readfirstlane(mp[2 * w + 1]);
            unsigned long long m = ((unsigned long long)hi << 32) | lo;
            while (m) {                            // wave-uniform scalar loop
                int i = (w << 6) + __builtin_ctzll(m);
                m &= (m - 1);
                h += sW[i * 64 + lane];            // conflict-free ds_read_b32
            }
        }
        // membrane update: match np fp32 semantics (mul, add separate; no fma)
        float mm = 0.9f * mem;
        mm = mm + h;
        float spk = (mm - 1.0f > 0.0f) ? 1.0f : 0.0f;
        mm = mm - spk;                             // subtract reset (threshold=1)
        mem = mm;

        outHid[(size_t)t * (BB * HID) + (size_t)b * HID + j] = spk;

        // layer-2 partial over this j-chunk
        float v0 = spk * w20;
        float v1 = spk * w21;
#pragma unroll
        for (int off = 32; off > 0; off >>= 1) {
            v0 += __shfl_xor(v0, off, 64);
            v1 += __shfl_xor(v1, off, 64);
        }
        if (lane == 0) {
            *reinterpret_cast<float2*>(part + (((size_t)t * 16 + jc) * BB + b) * 2) =
                make_float2(v0, v1);
        }
    }
}

__global__ __launch_bounds__(256) void k_h2(const float* __restrict__ part,
                                            const float* __restrict__ b2,
                                            float* __restrict__ h2) {
#pragma clang fp contract(off)
    int idx = blockIdx.x * 256 + threadIdx.x;     // 262144 = T*B*2
    int t = idx >> 8;
    int r = idx & 255;                            // b*2 + o
    int o = r & 1;
    float s = 0.0f;
#pragma unroll
    for (int c = 0; c < 16; ++c)
        s += part[(((size_t)t * 16 + c) << 8) + r];
    s += b2[o];
    h2[idx] = s;
}

__global__ __launch_bounds__(256) void k_scan(const float* __restrict__ h2,
                                              float* __restrict__ outSpk,
                                              float* __restrict__ outMem2) {
#pragma clang fp contract(off)
    const int tid = threadIdx.x;                  // b*2 + o
    float mem = 0.0f;
    float cur[8], nxt[8];
#pragma unroll
    for (int k = 0; k < 8; ++k) cur[k] = h2[k * 256 + tid];
    for (int t0 = 0; t0 < TT; t0 += 8) {
#pragma unroll
        for (int k = 0; k < 8; ++k) {
            int tn = t0 + 8 + k;
            nxt[k] = (tn < TT) ? h2[tn * 256 + tid] : 0.0f;
        }
#pragma unroll
        for (int k = 0; k < 8; ++k) {
            float mm = 0.9f * mem;
            mm = mm + cur[k];
            float spk = (mm - 1.0f > 0.0f) ? 1.0f : 0.0f;
            mm = mm - spk;
            mem = mm;
            outSpk[(t0 + k) * 256 + tid] = spk;
        }
#pragma unroll
        for (int k = 0; k < 8; ++k) cur[k] = nxt[k];
    }
    outMem2[tid] = mem;
}

extern "C" void kernel_launch(void* const* d_in, const int* in_sizes, int n_in,
                              void* d_out, int out_size, void* d_ws, size_t ws_size,
                              hipStream_t stream) {
    const float* x  = (const float*)d_in[0];
    const float* W1 = (const float*)d_in[1];
    const float* b1 = (const float*)d_in[2];
    const float* W2 = (const float*)d_in[3];
    const float* b2 = (const float*)d_in[4];
    float* out = (float*)d_out;

    char* ws = (char*)d_ws;                       // needs 22 MB total
    float* W1T                  = (float*)(ws);
    unsigned long long* masks   = (unsigned long long*)(ws + (1 << 20));
    float* part                 = (float*)(ws + (5 << 20));
    float* h2                   = (float*)(ws + (21 << 20));

    k_transpose<<<1024, 256, 0, stream>>>(W1, W1T);
    k_pack<<<131072, 256, 0, stream>>>(x, masks);
    k_snn<<<512, 256, 0, stream>>>(W1T, masks, b1, W2, out + OFF_HID, part);
    k_h2<<<1024, 256, 0, stream>>>(part, b2, h2);
    k_scan<<<1, 256, 0, stream>>>(h2, out, out + OFF_MEM2);
}

// Round 2
// 1623.438 us; speedup vs baseline: 1.7115x; 1.7115x over previous
//
#include <hip/hip_runtime.h>
#include <hip/hip_bf16.h>
#include <stdint.h>

// SNN forward (snntorch Leaky, subtract reset), T=1024 B=128 NIN=256 HID=1024.
// d_out: out_spikes [T,B,2] | hidden_spikes [T,B,HID] | mem2_f [B,2]
//
// Round-2: sparse gather made throughput-bound:
//  - k_pack builds per-(t,b) ascending u8 index lists (rank scatter) + count
//  - k_snn: 2 j per lane (ds_read_b64), 128-j chunk staged in 128KB LDS with
//    column permutation (lane pair = (j, j+64)) so the layer-2 butterfly trees
//    are bitwise-identical to round-1's; 8-deep batched reads; next-t prefetch.
//  - FP order identical to round-1 (absmax 0.0): bias-first ascending-i adds,
//    mul/add separate, same shuffle-xor reduction trees, 16-chunk k_h2.

#define TT  1024
#define BB  128
#define NIN 256
#define HID 1024

#define OFF_HID  262144ULL
#define OFF_MEM2 134479872ULL

__global__ __launch_bounds__(256) void k_transpose(const float* __restrict__ W1,
                                                   float* __restrict__ W1T) {
    int idx = blockIdx.x * 256 + threadIdx.x;     // 262144 elements
    int j = idx & (HID - 1);
    int i = idx >> 10;
    W1T[(size_t)i * HID + j] = W1[(size_t)j * NIN + i];
}

__global__ __launch_bounds__(256) void k_pack(const float* __restrict__ x,
                                              unsigned int* __restrict__ cntArr,
                                              unsigned char* __restrict__ idxArr,
                                              int slots) {
    size_t tb = blockIdx.x;                       // T*B blocks, 256 threads = i
    int tid = threadIdx.x;
    int lane = tid & 63, w = tid >> 6;
    float v = x[tb * NIN + tid];
    bool act = v > 0.5f;
    unsigned long long m = __ballot(act);
    __shared__ unsigned int wc[4];
    __shared__ unsigned char sIdx[96];
    if (lane == 0) wc[w] = (unsigned int)__popcll(m);
    __syncthreads();
    unsigned int off = 0;
#pragma unroll
    for (int k = 0; k < 4; ++k) if (k < w) off += wc[k];
    unsigned int cnt = wc[0] + wc[1] + wc[2] + wc[3];
    unsigned int rank = off + (unsigned int)__popcll(m & ((1ull << lane) - 1));
    if (act && rank < (unsigned int)slots) sIdx[rank] = (unsigned char)tid;
    __syncthreads();
    if (tid * 4 < slots)
        ((unsigned int*)(idxArr + tb * (size_t)slots))[tid] = ((const unsigned int*)sIdx)[tid];
    if (tid == 0) cntArr[tb] = cnt;
}

// Workgroup = 4 waves = 4 b's sharing one 128-j chunk (LDS 128KB, permuted:
// sW2[i][lane] = (W1T[i][jc*128+lane], W1T[i][jc*128+64+lane])).
// Grid = 32 bgroups x 8 jchunks = 256 wgs (1/CU).
__global__ __launch_bounds__(256) void k_snn(const float* __restrict__ W1T,
                                             const unsigned int* __restrict__ cntArr,
                                             const unsigned char* __restrict__ idxArr,
                                             const float* __restrict__ x,
                                             const float* __restrict__ b1,
                                             const float* __restrict__ W2,
                                             float* __restrict__ outHid,
                                             float* __restrict__ part,
                                             int slots) {
#pragma clang fp contract(off)
    const int jc   = blockIdx.x & 7;
    const int bg   = blockIdx.x >> 3;
    const int lane = threadIdx.x & 63;
    const int wave = threadIdx.x >> 6;
    const int b    = (bg << 2) + wave;
    const int j0   = (jc << 7) + lane;            // round-1 chunk 2*jc, lane pos
    const int j1   = j0 + 64;                     // round-1 chunk 2*jc+1, lane pos

    __shared__ float2 sW2[NIN * 64];              // 128 KB
    for (int p = threadIdx.x; p < NIN * 64; p += 256) {
        int i = p >> 6, l = p & 63;
        sW2[p] = make_float2(W1T[(size_t)i * HID + (jc << 7) + l],
                             W1T[(size_t)i * HID + (jc << 7) + 64 + l]);
    }
    __syncthreads();

    float mem0 = 0.0f, mem1 = 0.0f;
    const float bias0 = b1[j0], bias1 = b1[j1];
    const float w200 = W2[j0],        w201 = W2[j1];        // W2[0][.]
    const float w210 = W2[HID + j0],  w211 = W2[HID + j1];  // W2[1][.]
    const int ub = __builtin_amdgcn_readfirstlane(b);

    // prefetch t=0 index data
    unsigned int cnt_v  = cntArr[(size_t)ub];
    unsigned int vIdx_v = ((const unsigned int*)(idxArr + (size_t)ub * (size_t)slots))[lane & 31];

    for (int t = 0; t < TT; ++t) {
        unsigned int cnt  = (unsigned int)__builtin_amdgcn_readfirstlane((int)cnt_v);
        unsigned int vIdx = vIdx_v;

        // prefetch t+1 (clamped) — hides global latency under the gather
        int tn = (t + 1 < TT) ? t + 1 : t;
        size_t tbn = (size_t)tn * BB + ub;
        cnt_v  = cntArr[tbn];
        vIdx_v = ((const unsigned int*)(idxArr + tbn * (size_t)slots))[lane & 31];

        float h0 = bias0, h1 = bias1;
        unsigned int lim = cnt < (unsigned int)slots ? cnt : (unsigned int)slots;
        unsigned int kb = lim & ~7u;
        for (unsigned int kk = 0; kk < kb; kk += 8) {
            unsigned int d0 = (unsigned int)__builtin_amdgcn_readlane((int)vIdx, (int)(kk >> 2));
            unsigned int d1 = (unsigned int)__builtin_amdgcn_readlane((int)vIdx, (int)(kk >> 2) + 1);
            float2 wa = sW2[((d0      ) & 255) * 64 + lane];
            float2 wb = sW2[((d0 >>  8) & 255) * 64 + lane];
            float2 wc = sW2[((d0 >> 16) & 255) * 64 + lane];
            float2 wd = sW2[((d0 >> 24)      ) * 64 + lane];
            float2 we = sW2[((d1      ) & 255) * 64 + lane];
            float2 wf = sW2[((d1 >>  8) & 255) * 64 + lane];
            float2 wg = sW2[((d1 >> 16) & 255) * 64 + lane];
            float2 wh = sW2[((d1 >> 24)      ) * 64 + lane];
            h0 += wa.x; h1 += wa.y;   // ascending-i order, two chains
            h0 += wb.x; h1 += wb.y;
            h0 += wc.x; h1 += wc.y;
            h0 += wd.x; h1 += wd.y;
            h0 += we.x; h1 += we.y;
            h0 += wf.x; h1 += wf.y;
            h0 += wg.x; h1 += wg.y;
            h0 += wh.x; h1 += wh.y;
        }
        for (unsigned int kk = kb; kk < lim; ++kk) {
            unsigned int d = (unsigned int)__builtin_amdgcn_readlane((int)vIdx, (int)(kk >> 2));
            unsigned int i = (d >> ((kk & 3) * 8)) & 255;
            float2 wv = sW2[i * 64 + lane];
            h0 += wv.x; h1 += wv.y;
        }
        if (cnt > (unsigned int)slots) {          // ~never: overflow fallback
            const float* xr = x + ((size_t)t * BB + ub) * NIN;
            unsigned int skip = (unsigned int)slots;
            for (int w = 0; w < 4; ++w) {
                unsigned long long m = __ballot(xr[(w << 6) + lane] > 0.5f);
                unsigned int pc = (unsigned int)__popcll(m);
                if (skip >= pc) { skip -= pc; continue; }
                while (skip) { m &= m - 1; --skip; }
                while (m) {
                    int i = (w << 6) + __builtin_ctzll(m);
                    m &= m - 1;
                    float2 wv = sW2[i * 64 + lane];
                    h0 += wv.x; h1 += wv.y;
                }
            }
        }

        // membrane update (np fp32 semantics: mul, add separate)
        float mm0 = 0.9f * mem0; mm0 = mm0 + h0;
        float spk0 = (mm0 - 1.0f > 0.0f) ? 1.0f : 0.0f;
        mm0 = mm0 - spk0; mem0 = mm0;
        float mm1 = 0.9f * mem1; mm1 = mm1 + h1;
        float spk1 = (mm1 - 1.0f > 0.0f) ? 1.0f : 0.0f;
        mm1 = mm1 - spk1; mem1 = mm1;

        float* orow = outHid + (size_t)t * (BB * HID) + (size_t)b * HID;
        orow[j0] = spk0;
        orow[j1] = spk1;

        // layer-2 partials: two butterflies per chunk, identical trees to round-1
        float r00 = spk0 * w200, r01 = spk0 * w210;
        float r10 = spk1 * w201, r11 = spk1 * w211;
#pragma unroll
        for (int off = 32; off > 0; off >>= 1) {
            r00 += __shfl_xor(r00, off, 64);
            r01 += __shfl_xor(r01, off, 64);
            r10 += __shfl_xor(r10, off, 64);
            r11 += __shfl_xor(r11, off, 64);
        }
        if (lane == 0) {
            *reinterpret_cast<float2*>(part + (((size_t)t * 16 + 2 * jc    ) * BB + b) * 2) = make_float2(r00, r01);
            *reinterpret_cast<float2*>(part + (((size_t)t * 16 + 2 * jc + 1) * BB + b) * 2) = make_float2(r10, r11);
        }
    }
}

__global__ __launch_bounds__(256) void k_h2(const float* __restrict__ part,
                                            const float* __restrict__ b2,
                                            float* __restrict__ h2) {
#pragma clang fp contract(off)
    int idx = blockIdx.x * 256 + threadIdx.x;     // 262144 = T*B*2
    int t = idx >> 8;
    int r = idx & 255;                            // b*2 + o
    int o = r & 1;
    float s = 0.0f;
#pragma unroll
    for (int c = 0; c < 16; ++c)
        s += part[(((size_t)t * 16 + c) << 8) + r];
    s += b2[o];
    h2[idx] = s;
}

__global__ __launch_bounds__(256) void k_scan(const float* __restrict__ h2,
                                              float* __restrict__ outSpk,
                                              float* __restrict__ outMem2) {
#pragma clang fp contract(off)
    const int tid = threadIdx.x;                  // b*2 + o
    float mem = 0.0f;
    float cur[8], nxt[8];
#pragma unroll
    for (int k = 0; k < 8; ++k) cur[k] = h2[k * 256 + tid];
    for (int t0 = 0; t0 < TT; t0 += 8) {
#pragma unroll
        for (int k = 0; k < 8; ++k) {
            int tn = t0 + 8 + k;
            nxt[k] = (tn < TT) ? h2[tn * 256 + tid] : 0.0f;
        }
#pragma unroll
        for (int k = 0; k < 8; ++k) {
            float mm = 0.9f * mem;
            mm = mm + cur[k];
            float spk = (mm - 1.0f > 0.0f) ? 1.0f : 0.0f;
            mm = mm - spk;
            mem = mm;
            outSpk[(t0 + k) * 256 + tid] = spk;
        }
#pragma unroll
        for (int k = 0; k < 8; ++k) cur[k] = nxt[k];
    }
    outMem2[tid] = mem;
}

extern "C" void kernel_launch(void* const* d_in, const int* in_sizes, int n_in,
                              void* d_out, int out_size, void* d_ws, size_t ws_size,
                              hipStream_t stream) {
    const float* x  = (const float*)d_in[0];
    const float* W1 = (const float*)d_in[1];
    const float* b1 = (const float*)d_in[2];
    const float* W2 = (const float*)d_in[3];
    const float* b2 = (const float*)d_in[4];
    float* out = (float*)d_out;

    char* ws = (char*)d_ws;
    float*              W1T  = (float*)(ws);                                   // 1 MB
    unsigned int*       cnt  = (unsigned int*)(ws + (1 << 20));                // 512 KB
    unsigned char*      idx  = (unsigned char*)(ws + (1 << 20) + (1 << 19));   // 131072*slots

    // size the index lists to the workspace (fallback path covers overflow)
    size_t fixedB = (size_t)(1 << 20) + (1 << 19) + (16 << 20) + (1 << 20);
    size_t avail  = ws_size > fixedB ? ws_size - fixedB : 0;
    long   s      = (long)((avail / 131072) & ~(size_t)7);
    int slots = (int)(s > 96 ? 96 : (s < 8 ? 8 : s));

    char* after_idx = ws + (1 << 20) + (1 << 19) + (size_t)131072 * (size_t)slots;
    float* part = (float*)after_idx;               // 16 MB
    float* h2   = (float*)(after_idx + (16 << 20));// 1 MB

    k_transpose<<<1024, 256, 0, stream>>>(W1, W1T);
    k_pack<<<131072, 256, 0, stream>>>(x, cnt, idx, slots);
    k_snn<<<256, 256, 0, stream>>>(W1T, cnt, idx, x, b1, W2, out + OFF_HID, part, slots);
    k_h2<<<1024, 256, 0, stream>>>(part, b2, h2);
    k_scan<<<1, 256, 0, stream>>>(h2, out, out + OFF_MEM2);
}

// Round 3
// 1597.988 us; speedup vs baseline: 1.7387x; 1.0159x over previous
//
#include <hip/hip_runtime.h>
#include <hip/hip_bf16.h>
#include <stdint.h>

// SNN forward (snntorch Leaky, subtract reset), T=1024 B=128 NIN=256 HID=1024.
// d_out: out_spikes [T,B,2] | hidden_spikes [T,B,HID] | mem2_f [B,2]
//
// Round-3: maximize wave parallelism in the recurrence kernel, evict all
// serial cross-lane work from it:
//  - k_snn: 1 j/lane, 64KB LDS tile, 512 wgs x 4 waves = 2 waves/SIMD,
//    2 wg/CU. Inner loop = batched LDS gathers + ascending adds + membrane +
//    one coalesced spike store. No shuffles, no part stores.
//  - k_h2: recomputes layer-2 from hidden spikes (in d_out) with the
//    bit-identical tree: per-64-chunk mul -> xor-butterfly(32..1) ->
//    ascending 16-chunk sum -> +b2. High occupancy hides swizzle latency.
//  - FP order identical to rounds 1/2 (absmax 0.0).

#define TT  1024
#define BB  128
#define NIN 256
#define HID 1024

#define OFF_HID  262144ULL
#define OFF_MEM2 134479872ULL

__global__ __launch_bounds__(256) void k_transpose(const float* __restrict__ W1,
                                                   float* __restrict__ W1T) {
    int idx = blockIdx.x * 256 + threadIdx.x;     // 262144 elements
    int j = idx & (HID - 1);
    int i = idx >> 10;
    W1T[(size_t)i * HID + j] = W1[(size_t)j * NIN + i];
}

__global__ __launch_bounds__(256) void k_pack(const float* __restrict__ x,
                                              unsigned int* __restrict__ cntArr,
                                              unsigned char* __restrict__ idxArr,
                                              int slots) {
    size_t tb = blockIdx.x;                       // T*B blocks, 256 threads = i
    int tid = threadIdx.x;
    int lane = tid & 63, w = tid >> 6;
    float v = x[tb * NIN + tid];
    bool act = v > 0.5f;
    unsigned long long m = __ballot(act);
    __shared__ unsigned int wc[4];
    __shared__ unsigned char sIdx[96];
    if (lane == 0) wc[w] = (unsigned int)__popcll(m);
    __syncthreads();
    unsigned int off = 0;
#pragma unroll
    for (int k = 0; k < 4; ++k) if (k < w) off += wc[k];
    unsigned int cnt = wc[0] + wc[1] + wc[2] + wc[3];
    unsigned int rank = off + (unsigned int)__popcll(m & ((1ull << lane) - 1));
    if (act && rank < (unsigned int)slots) sIdx[rank] = (unsigned char)tid;
    __syncthreads();
    if (tid * 4 < slots)
        ((unsigned int*)(idxArr + tb * (size_t)slots))[tid] = ((const unsigned int*)sIdx)[tid];
    if (tid == 0) cntArr[tb] = cnt;
}

// Workgroup = 4 waves = 4 b's sharing one 64-j chunk of W1T (64KB LDS).
// Grid = 32 bgroups x 16 jchunks = 512 wgs -> 2 wg/CU, 2 waves/SIMD.
__global__ __launch_bounds__(256) void k_snn(const float* __restrict__ W1T,
                                             const unsigned int* __restrict__ cntArr,
                                             const unsigned char* __restrict__ idxArr,
                                             const float* __restrict__ x,
                                             const float* __restrict__ b1,
                                             float* __restrict__ outHid,
                                             int slots) {
#pragma clang fp contract(off)
    const int jc   = blockIdx.x & 15;
    const int bg   = blockIdx.x >> 4;
    const int lane = threadIdx.x & 63;
    const int wave = threadIdx.x >> 6;
    const int b    = (bg << 2) + wave;
    const int j    = (jc << 6) + lane;

    __shared__ float sW[NIN * 64];                // 64 KB: W1T[:, jc*64 .. +64)
    for (int r = threadIdx.x; r < NIN * 16; r += 256) {
        int i = r >> 4, q = r & 15;
        float4 v = *reinterpret_cast<const float4*>(W1T + (size_t)i * HID + (jc << 6) + (q << 2));
        *reinterpret_cast<float4*>(sW + i * 64 + (q << 2)) = v;
    }
    __syncthreads();

    float mem        = 0.0f;
    const float bias = b1[j];
    const int   ub   = __builtin_amdgcn_readfirstlane(b);

    // prefetch t=0 index data
    unsigned int cnt_v  = cntArr[(size_t)ub];
    unsigned int vIdx_v = ((const unsigned int*)(idxArr + (size_t)ub * (size_t)slots))[lane & 31];

    for (int t = 0; t < TT; ++t) {
        unsigned int cnt  = (unsigned int)__builtin_amdgcn_readfirstlane((int)cnt_v);
        unsigned int vIdx = vIdx_v;

        // prefetch t+1 (clamped) — hides global latency under the gather
        int tn = (t + 1 < TT) ? t + 1 : t;
        size_t tbn = (size_t)tn * BB + ub;
        cnt_v  = cntArr[tbn];
        vIdx_v = ((const unsigned int*)(idxArr + tbn * (size_t)slots))[lane & 31];

        float h = bias;
        unsigned int lim = cnt < (unsigned int)slots ? cnt : (unsigned int)slots;
        unsigned int kb = lim & ~7u;
        for (unsigned int kk = 0; kk < kb; kk += 8) {
            unsigned int d0 = (unsigned int)__builtin_amdgcn_readlane((int)vIdx, (int)(kk >> 2));
            unsigned int d1 = (unsigned int)__builtin_amdgcn_readlane((int)vIdx, (int)(kk >> 2) + 1);
            float wa = sW[((d0      ) & 255) * 64 + lane];
            float wb = sW[((d0 >>  8) & 255) * 64 + lane];
            float wc = sW[((d0 >> 16) & 255) * 64 + lane];
            float wd = sW[((d0 >> 24)      ) * 64 + lane];
            float we = sW[((d1      ) & 255) * 64 + lane];
            float wf = sW[((d1 >>  8) & 255) * 64 + lane];
            float wg = sW[((d1 >> 16) & 255) * 64 + lane];
            float wh = sW[((d1 >> 24)      ) * 64 + lane];
            h += wa; h += wb; h += wc; h += wd;   // ascending-i order
            h += we; h += wf; h += wg; h += wh;
        }
        for (unsigned int kk = kb; kk < lim; ++kk) {
            unsigned int d = (unsigned int)__builtin_amdgcn_readlane((int)vIdx, (int)(kk >> 2));
            unsigned int i = (d >> ((kk & 3) * 8)) & 255;
            h += sW[i * 64 + lane];
        }
        if (cnt > (unsigned int)slots) {          // ~never: overflow fallback
            const float* xr = x + ((size_t)t * BB + ub) * NIN;
            unsigned int skip = (unsigned int)slots;
            for (int w = 0; w < 4; ++w) {
                unsigned long long m = __ballot(xr[(w << 6) + lane] > 0.5f);
                unsigned int pc = (unsigned int)__popcll(m);
                if (skip >= pc) { skip -= pc; continue; }
                while (skip) { m &= m - 1; --skip; }
                while (m) {
                    int i = (w << 6) + __builtin_ctzll(m);
                    m &= m - 1;
                    h += sW[i * 64 + lane];
                }
            }
        }

        // membrane update (np fp32 semantics: mul, add separate)
        float mm = 0.9f * mem;
        mm = mm + h;
        float spk = (mm - 1.0f > 0.0f) ? 1.0f : 0.0f;
        mm = mm - spk;
        mem = mm;

        outHid[(size_t)t * (BB * HID) + (size_t)b * HID + j] = spk;
    }
}

// One wave per (t,b): reproduce the round-1/2 layer-2 reduction bit-exactly:
// per chunk c (ascending 0..15): r = spk[c*64+lane]*W2[o][c*64+lane],
// xor-butterfly offs 32,16,8,4,2,1, accumulate; then + b2[o].
__global__ __launch_bounds__(256) void k_h2(const float* __restrict__ spk,
                                            const float* __restrict__ W2,
                                            const float* __restrict__ b2,
                                            float* __restrict__ h2) {
#pragma clang fp contract(off)
    const int lane = threadIdx.x & 63;
    const int wave = threadIdx.x >> 6;
    size_t tb = (size_t)blockIdx.x * 4 + wave;    // t*B + b
    const float* row = spk + tb * HID;
    float s0 = 0.0f, s1 = 0.0f;
#pragma unroll
    for (int c = 0; c < 16; ++c) {
        float v  = row[c * 64 + lane];
        float r0 = v * W2[c * 64 + lane];
        float r1 = v * W2[HID + c * 64 + lane];
#pragma unroll
        for (int off = 32; off > 0; off >>= 1) {
            r0 += __shfl_xor(r0, off, 64);
            r1 += __shfl_xor(r1, off, 64);
        }
        s0 += r0;
        s1 += r1;
    }
    s0 += b2[0];
    s1 += b2[1];
    if (lane == 0)
        *reinterpret_cast<float2*>(h2 + tb * 2) = make_float2(s0, s1);
}

__global__ __launch_bounds__(256) void k_scan(const float* __restrict__ h2,
                                              float* __restrict__ outSpk,
                                              float* __restrict__ outMem2) {
#pragma clang fp contract(off)
    const int tid = threadIdx.x;                  // b*2 + o
    float mem = 0.0f;
    float cur[8], nxt[8];
#pragma unroll
    for (int k = 0; k < 8; ++k) cur[k] = h2[k * 256 + tid];
    for (int t0 = 0; t0 < TT; t0 += 8) {
#pragma unroll
        for (int k = 0; k < 8; ++k) {
            int tn = t0 + 8 + k;
            nxt[k] = (tn < TT) ? h2[tn * 256 + tid] : 0.0f;
        }
#pragma unroll
        for (int k = 0; k < 8; ++k) {
            float mm = 0.9f * mem;
            mm = mm + cur[k];
            float spk = (mm - 1.0f > 0.0f) ? 1.0f : 0.0f;
            mm = mm - spk;
            mem = mm;
            outSpk[(t0 + k) * 256 + tid] = spk;
        }
#pragma unroll
        for (int k = 0; k < 8; ++k) cur[k] = nxt[k];
    }
    outMem2[tid] = mem;
}

extern "C" void kernel_launch(void* const* d_in, const int* in_sizes, int n_in,
                              void* d_out, int out_size, void* d_ws, size_t ws_size,
                              hipStream_t stream) {
    const float* x  = (const float*)d_in[0];
    const float* W1 = (const float*)d_in[1];
    const float* b1 = (const float*)d_in[2];
    const float* W2 = (const float*)d_in[3];
    const float* b2 = (const float*)d_in[4];
    float* out = (float*)d_out;

    char* ws = (char*)d_ws;
    float*         W1T = (float*)(ws);                                 // 1 MB
    unsigned int*  cnt = (unsigned int*)(ws + (1 << 20));              // 512 KB
    unsigned char* idx = (unsigned char*)(ws + (1 << 20) + (1 << 19)); // 131072*slots

    // size the index lists to the workspace (fallback path covers overflow)
    size_t fixedB = (size_t)(1 << 20) + (1 << 19) + (1 << 20);
    size_t avail  = ws_size > fixedB ? ws_size - fixedB : 0;
    long   s      = (long)((avail / 131072) & ~(size_t)7);
    int slots = (int)(s > 96 ? 96 : (s < 8 ? 8 : s));

    float* h2 = (float*)(ws + (1 << 20) + (1 << 19) + (size_t)131072 * (size_t)slots); // 1 MB

    k_transpose<<<1024, 256, 0, stream>>>(W1, W1T);
    k_pack<<<131072, 256, 0, stream>>>(x, cnt, idx, slots);
    k_snn<<<512, 256, 0, stream>>>(W1T, cnt, idx, x, b1, out + OFF_HID, slots);
    k_h2<<<32768, 256, 0, stream>>>(out + OFF_HID, W2, b2, h2);
    k_scan<<<1, 256, 0, stream>>>(h2, out, out + OFF_MEM2);
}